// Round 1
// baseline (762.462 us; speedup 1.0000x reference)
//
#include <hip/hip_runtime.h>

#define N_NODES 50000
#define N_EDGES 800000
#define IN_DIM 128
#define HID 64
#define N_GRAPHS 256

// ---------------- proj: h = relu(x @ Wp + bp), one wave per node ----------------
__global__ __launch_bounds__(256) void proj_kernel(
    const float* __restrict__ x, const float* __restrict__ Wp,
    const float* __restrict__ bp, float* __restrict__ h) {
  __shared__ float sW[IN_DIM * HID];  // 32 KB
  __shared__ float sb[HID];
  for (int i = threadIdx.x; i < IN_DIM * HID; i += 256) sW[i] = Wp[i];
  if (threadIdx.x < HID) sb[threadIdx.x] = bp[threadIdx.x];
  __syncthreads();
  const int wave = threadIdx.x >> 6, lane = threadIdx.x & 63;
  const int nwaves = gridDim.x * 4;
  for (int n = blockIdx.x * 4 + wave; n < N_NODES; n += nwaves) {
    float x0 = x[(size_t)n * IN_DIM + lane];
    float x1 = x[(size_t)n * IN_DIM + 64 + lane];
    float acc = sb[lane];
#pragma unroll
    for (int k = 0; k < 64; ++k) acc = fmaf(__shfl(x0, k), sW[k * HID + lane], acc);
#pragma unroll
    for (int k = 0; k < 64; ++k) acc = fmaf(__shfl(x1, k), sW[(64 + k) * HID + lane], acc);
    h[(size_t)n * HID + lane] = fmaxf(acc, 0.0f);
  }
}

// ---------------- scatter: agg[dst] += h[src], one wave per edge ----------------
__global__ __launch_bounds__(256) void scatter_kernel(
    const int* __restrict__ src, const int* __restrict__ dst,
    const float* __restrict__ h, float* __restrict__ agg) {
  const int lane = threadIdx.x & 63;
  const int wv = (blockIdx.x * 256 + threadIdx.x) >> 6;
  const int nw = (gridDim.x * 256) >> 6;
  for (int e = wv; e < N_EDGES; e += nw) {
    int s = src[e], d = dst[e];
    float v = h[(size_t)s * HID + lane];
    unsafeAtomicAdd(&agg[(size_t)d * HID + lane], v);
  }
}

// ------- mlp: out = relu( relu((h+agg) @ W1 + b1) @ W2 + b2 ), wave per node -------
__global__ __launch_bounds__(256) void mlp_kernel(
    const float* __restrict__ h, const float* __restrict__ agg,
    const float* __restrict__ W1, const float* __restrict__ b1,
    const float* __restrict__ W2, const float* __restrict__ b2,
    float* __restrict__ out) {
  __shared__ float sW1[HID * HID];  // 16 KB
  __shared__ float sW2[HID * HID];  // 16 KB
  __shared__ float sb1[HID], sb2[HID];
  for (int i = threadIdx.x; i < HID * HID; i += 256) {
    sW1[i] = W1[i];
    sW2[i] = W2[i];
  }
  if (threadIdx.x < HID) {
    sb1[threadIdx.x] = b1[threadIdx.x];
    sb2[threadIdx.x] = b2[threadIdx.x];
  }
  __syncthreads();
  const int wave = threadIdx.x >> 6, lane = threadIdx.x & 63;
  const int nwaves = gridDim.x * 4;
  for (int n = blockIdx.x * 4 + wave; n < N_NODES; n += nwaves) {
    float in = h[(size_t)n * HID + lane] + agg[(size_t)n * HID + lane];
    float acc = sb1[lane];
#pragma unroll
    for (int k = 0; k < 64; ++k) acc = fmaf(__shfl(in, k), sW1[k * HID + lane], acc);
    float t = fmaxf(acc, 0.0f);
    acc = sb2[lane];
#pragma unroll
    for (int k = 0; k < 64; ++k) acc = fmaf(__shfl(t, k), sW2[k * HID + lane], acc);
    out[(size_t)n * HID + lane] = fmaxf(acc, 0.0f);
  }
}

// ---------------- pool: atomic segment sum over sorted batch ids ----------------
__global__ __launch_bounds__(256) void pool_kernel(
    const float* __restrict__ h, const int* __restrict__ batch,
    float* __restrict__ sums, float* __restrict__ counts) {
  const int lane = threadIdx.x & 63;
  const int wv = (blockIdx.x * 256 + threadIdx.x) >> 6;
  const int nw = (gridDim.x * 256) >> 6;
  for (int n = wv; n < N_NODES; n += nw) {
    int g = batch[n];
    unsafeAtomicAdd(&sums[(size_t)g * HID + lane], h[(size_t)n * HID + lane]);
    if (lane == 0) unsafeAtomicAdd(&counts[g], 1.0f);
  }
}

__global__ __launch_bounds__(256) void finalize_kernel(
    const float* __restrict__ sums, const float* __restrict__ counts,
    float* __restrict__ out) {
  int i = blockIdx.x * 256 + threadIdx.x;
  if (i < N_GRAPHS * HID) {
    float c = counts[i >> 6];
    out[i] = sums[i] / fmaxf(c, 1.0f);
  }
}

extern "C" void kernel_launch(void* const* d_in, const int* in_sizes, int n_in,
                              void* d_out, int out_size, void* d_ws, size_t ws_size,
                              hipStream_t stream) {
  const float* x    = (const float*)d_in[0];
  const int*   edge = (const int*)d_in[1];
  const int*   batch= (const int*)d_in[2];
  const float* Wp   = (const float*)d_in[3];
  const float* bp   = (const float*)d_in[4];
  const float* W1_0 = (const float*)d_in[5];
  const float* b1_0 = (const float*)d_in[6];
  const float* W2_0 = (const float*)d_in[7];
  const float* b2_0 = (const float*)d_in[8];
  const float* W1_1 = (const float*)d_in[9];
  const float* b1_1 = (const float*)d_in[10];
  const float* W2_1 = (const float*)d_in[11];
  const float* b2_1 = (const float*)d_in[12];
  const int* src = edge;
  const int* dst = edge + N_EDGES;
  float* out = (float*)d_out;

  const size_t NB = (size_t)N_NODES * HID;  // 3.2M floats per buffer
  float* bufA   = (float*)d_ws;
  float* bufB   = bufA + NB;
  float* bufC   = bufB + NB;
  float* counts = bufC + NB;  // 256 floats

  dim3 blk(256);

  // h0 = relu(x @ Wp + bp)            -> bufA
  proj_kernel<<<2048, blk, 0, stream>>>(x, Wp, bp, bufA);

  // layer 0: agg -> bufB, out -> bufC
  hipMemsetAsync(bufB, 0, NB * sizeof(float), stream);
  scatter_kernel<<<4096, blk, 0, stream>>>(src, dst, bufA, bufB);
  mlp_kernel<<<2048, blk, 0, stream>>>(bufA, bufB, W1_0, b1_0, W2_0, b2_0, bufC);

  // layer 1: agg -> bufB, out -> bufA
  hipMemsetAsync(bufB, 0, NB * sizeof(float), stream);
  scatter_kernel<<<4096, blk, 0, stream>>>(src, dst, bufC, bufB);
  mlp_kernel<<<2048, blk, 0, stream>>>(bufC, bufB, W1_1, b1_1, W2_1, b2_1, bufA);

  // global mean pool: sums -> bufB (reused), counts -> counts
  hipMemsetAsync(bufB, 0, (size_t)N_GRAPHS * HID * sizeof(float), stream);
  hipMemsetAsync(counts, 0, N_GRAPHS * sizeof(float), stream);
  pool_kernel<<<512, blk, 0, stream>>>(bufA, batch, bufB, counts);
  finalize_kernel<<<(N_GRAPHS * HID + 255) / 256, blk, 0, stream>>>(bufB, counts, out);
}

// Round 2
// 656.546 us; speedup vs baseline: 1.1613x; 1.1613x over previous
//
#include <hip/hip_runtime.h>

#define N_NODES 50000
#define N_EDGES 800000
#define IN_DIM 128
#define HID 64
#define N_GRAPHS 256

// ---------------- proj: h = relu(x @ Wp + bp), one wave per node ----------------
__global__ __launch_bounds__(256) void proj_kernel(
    const float* __restrict__ x, const float* __restrict__ Wp,
    const float* __restrict__ bp, float* __restrict__ h) {
  __shared__ float sW[IN_DIM * HID];  // 32 KB
  __shared__ float sb[HID];
  for (int i = threadIdx.x; i < IN_DIM * HID; i += 256) sW[i] = Wp[i];
  if (threadIdx.x < HID) sb[threadIdx.x] = bp[threadIdx.x];
  __syncthreads();
  const int wave = threadIdx.x >> 6, lane = threadIdx.x & 63;
  const int nwaves = gridDim.x * 4;
  for (int n = blockIdx.x * 4 + wave; n < N_NODES; n += nwaves) {
    float x0 = x[(size_t)n * IN_DIM + lane];
    float x1 = x[(size_t)n * IN_DIM + 64 + lane];
    float acc = sb[lane];
#pragma unroll
    for (int k = 0; k < 64; ++k) acc = fmaf(__shfl(x0, k), sW[k * HID + lane], acc);
#pragma unroll
    for (int k = 0; k < 64; ++k) acc = fmaf(__shfl(x1, k), sW[(64 + k) * HID + lane], acc);
    h[(size_t)n * HID + lane] = fmaxf(acc, 0.0f);
  }
}

// ---------------- CSR build: histogram -> scan -> fill ----------------
__global__ __launch_bounds__(256) void hist_kernel(const int* __restrict__ dst,
                                                   int* __restrict__ deg) {
  int i = blockIdx.x * 256 + threadIdx.x;
  if (i < N_EDGES) atomicAdd(&deg[dst[i]], 1);
}

__global__ __launch_bounds__(1024) void scan_kernel(const int* __restrict__ deg,
                                                    int* __restrict__ off,
                                                    int* __restrict__ cursor) {
  // single block of 1024 threads, exclusive scan over N_NODES degrees
  __shared__ int ssum[1024];
  const int CH = (N_NODES + 1023) / 1024;  // 49
  const int t = threadIdx.x;
  const int base = t * CH;
  int s = 0;
  for (int i = 0; i < CH; ++i) {
    int n = base + i;
    if (n < N_NODES) s += deg[n];
  }
  ssum[t] = s;
  __syncthreads();
  for (int ofs = 1; ofs < 1024; ofs <<= 1) {
    int v = (t >= ofs) ? ssum[t - ofs] : 0;
    __syncthreads();
    ssum[t] += v;
    __syncthreads();
  }
  int run = (t == 0) ? 0 : ssum[t - 1];  // exclusive prefix of this chunk
  for (int i = 0; i < CH; ++i) {
    int n = base + i;
    if (n < N_NODES) {
      off[n] = run;
      cursor[n] = run;
      run += deg[n];
    }
  }
  if (t == 1023) off[N_NODES] = run;
}

__global__ __launch_bounds__(256) void fill_kernel(const int* __restrict__ src,
                                                   const int* __restrict__ dst,
                                                   int* __restrict__ cursor,
                                                   int* __restrict__ csr) {
  int i = blockIdx.x * 256 + threadIdx.x;
  if (i < N_EDGES) {
    int p = atomicAdd(&cursor[dst[i]], 1);
    csr[p] = src[i];
  }
}

// ---- fused GIN layer: out = relu( relu((h + gather_sum) @ W1 + b1) @ W2 + b2 ) ----
__global__ __launch_bounds__(256) void gin_fused_kernel(
    const float* __restrict__ h, const int* __restrict__ off,
    const int* __restrict__ csr, const float* __restrict__ W1,
    const float* __restrict__ b1, const float* __restrict__ W2,
    const float* __restrict__ b2, float* __restrict__ out) {
  __shared__ float sW1[HID * HID];  // 16 KB
  __shared__ float sW2[HID * HID];  // 16 KB
  __shared__ float sb1[HID], sb2[HID];
  for (int i = threadIdx.x; i < HID * HID; i += 256) {
    sW1[i] = W1[i];
    sW2[i] = W2[i];
  }
  if (threadIdx.x < HID) {
    sb1[threadIdx.x] = b1[threadIdx.x];
    sb2[threadIdx.x] = b2[threadIdx.x];
  }
  __syncthreads();
  const int wave = threadIdx.x >> 6, lane = threadIdx.x & 63;
  const int nwaves = gridDim.x * 4;
  for (int n = blockIdx.x * 4 + wave; n < N_NODES; n += nwaves) {
    const int o0 = off[n], o1 = off[n + 1];
    float agg = h[(size_t)n * HID + lane];  // self (eps = 0)
    for (int e0 = o0; e0 < o1; e0 += 64) {
      const int cnt = min(64, o1 - e0);
      int idxv = (lane < cnt) ? csr[e0 + lane] : 0;
      int k = 0;
      for (; k + 4 <= cnt; k += 4) {
        int i0 = __shfl(idxv, k + 0), i1 = __shfl(idxv, k + 1);
        int i2 = __shfl(idxv, k + 2), i3 = __shfl(idxv, k + 3);
        float v0 = h[(size_t)i0 * HID + lane];
        float v1 = h[(size_t)i1 * HID + lane];
        float v2 = h[(size_t)i2 * HID + lane];
        float v3 = h[(size_t)i3 * HID + lane];
        agg += v0;
        agg += v1;
        agg += v2;
        agg += v3;
      }
      for (; k < cnt; ++k) {
        int idx = __shfl(idxv, k);
        agg += h[(size_t)idx * HID + lane];
      }
    }
    float acc = sb1[lane];
#pragma unroll
    for (int k = 0; k < 64; ++k) acc = fmaf(__shfl(agg, k), sW1[k * HID + lane], acc);
    float t = fmaxf(acc, 0.0f);
    acc = sb2[lane];
#pragma unroll
    for (int k = 0; k < 64; ++k) acc = fmaf(__shfl(t, k), sW2[k * HID + lane], acc);
    out[(size_t)n * HID + lane] = fmaxf(acc, 0.0f);
  }
}

// ------- pool: batch is sorted -> one block per graph, binary-search range -------
__global__ __launch_bounds__(256) void pool_kernel(const float* __restrict__ h,
                                                   const int* __restrict__ batch,
                                                   float* __restrict__ out) {
  const int g = blockIdx.x;
  // lower_bound(batch, g) and lower_bound(batch, g+1)
  int lo = 0, hi = N_NODES;
  while (lo < hi) {
    int mid = (lo + hi) >> 1;
    if (batch[mid] < g) lo = mid + 1; else hi = mid;
  }
  const int s = lo;
  hi = N_NODES;
  while (lo < hi) {
    int mid = (lo + hi) >> 1;
    if (batch[mid] < g + 1) lo = mid + 1; else hi = mid;
  }
  const int e = lo;
  const int wave = threadIdx.x >> 6, lane = threadIdx.x & 63;
  float acc = 0.0f;
  for (int n = s + wave; n < e; n += 4) acc += h[(size_t)n * HID + lane];
  __shared__ float red[4][HID];
  red[wave][lane] = acc;
  __syncthreads();
  if (wave == 0) {
    float v = red[0][lane] + red[1][lane] + red[2][lane] + red[3][lane];
    float cnt = (float)(e - s);
    out[(size_t)g * HID + lane] = v / fmaxf(cnt, 1.0f);
  }
}

extern "C" void kernel_launch(void* const* d_in, const int* in_sizes, int n_in,
                              void* d_out, int out_size, void* d_ws, size_t ws_size,
                              hipStream_t stream) {
  const float* x    = (const float*)d_in[0];
  const int*   edge = (const int*)d_in[1];
  const int*   batch= (const int*)d_in[2];
  const float* Wp   = (const float*)d_in[3];
  const float* bp   = (const float*)d_in[4];
  const float* W1_0 = (const float*)d_in[5];
  const float* b1_0 = (const float*)d_in[6];
  const float* W2_0 = (const float*)d_in[7];
  const float* b2_0 = (const float*)d_in[8];
  const float* W1_1 = (const float*)d_in[9];
  const float* b1_1 = (const float*)d_in[10];
  const float* W2_1 = (const float*)d_in[11];
  const float* b2_1 = (const float*)d_in[12];
  const int* src = edge;
  const int* dst = edge + N_EDGES;
  float* out = (float*)d_out;

  const size_t NB = (size_t)N_NODES * HID;  // 3.2M floats per node buffer
  float* bufA = (float*)d_ws;
  float* bufB = bufA + NB;
  int* deg    = (int*)(bufB + NB);
  int* off    = deg + N_NODES;
  int* cursor = off + N_NODES + 1;
  int* csr    = cursor + N_NODES;  // 800000 ints

  dim3 blk(256);
  const int EG = (N_EDGES + 255) / 256;  // 3125

  // CSR build (independent of proj)
  hipMemsetAsync(deg, 0, N_NODES * sizeof(int), stream);
  hist_kernel<<<EG, blk, 0, stream>>>(dst, deg);
  scan_kernel<<<1, 1024, 0, stream>>>(deg, off, cursor);
  fill_kernel<<<EG, blk, 0, stream>>>(src, dst, cursor, csr);

  // h0 = relu(x @ Wp + bp) -> bufA
  proj_kernel<<<2048, blk, 0, stream>>>(x, Wp, bp, bufA);

  // layer 0: bufA -> bufB ; layer 1: bufB -> bufA
  gin_fused_kernel<<<12500, blk, 0, stream>>>(bufA, off, csr, W1_0, b1_0, W2_0, b2_0, bufB);
  gin_fused_kernel<<<12500, blk, 0, stream>>>(bufB, off, csr, W1_1, b1_1, W2_1, b2_1, bufA);

  // global mean pool, one block per graph
  pool_kernel<<<N_GRAPHS, blk, 0, stream>>>(bufA, batch, out);
}